// Round 5
// baseline (496.293 us; speedup 1.0000x reference)
//
#include <hip/hip_runtime.h>

#define TOK 4096
#define HD 1024
#define ID 4096
#define NE 8

typedef __attribute__((ext_vector_type(4))) float f32x4;
typedef __attribute__((ext_vector_type(8))) __bf16 bf16x8;
typedef __attribute__((ext_vector_type(8))) unsigned short u16x8;

// byte address within a 128B-stride row region, T2 XOR swizzle (write+read use same involution)
#define SWZ(row, boff) ((((row) << 7) + ((boff) ^ (((row) & 7) << 4))))

// compiler emits v_cvt_pk_bf16_f32 (RNE) for scalar casts -- do NOT hand-roll (m240)
__device__ __forceinline__ bf16x8 pack8(f32x4 a, f32x4 b) {
  bf16x8 r;
#pragma unroll
  for (int i = 0; i < 4; ++i) { r[i] = (__bf16)a[i]; r[i + 4] = (__bf16)b[i]; }
  return r;
}

__device__ __forceinline__ float gelu_tanh(float g) {
  float z = 0.7978845608028654f * (g + 0.044715f * g * g * g);
  float t = __expf(-2.0f * z);
  return g / (1.0f + t);
}

// barrier that does NOT drain vmcnt: LDS ordering via lgkmcnt(0), global prefetch stays in flight
__device__ __forceinline__ void bar_lgkm() {
  asm volatile("s_waitcnt lgkmcnt(0)" ::: "memory");
  __builtin_amdgcn_s_barrier();
}

__global__ void init_k(int* __restrict__ meta) {
  if (threadIdx.x < 16) meta[threadIdx.x] = 0;
}

__global__ void router_k(const float* __restrict__ x, const float* __restrict__ gw,
                         float* __restrict__ logits, int* __restrict__ top1) {
  const int wid = threadIdx.x >> 6;
  const int lane = threadIdx.x & 63;
  const int t = blockIdx.x * 4 + wid;
  const float* xr = x + (size_t)t * HD;
  float acc[NE];
#pragma unroll
  for (int e = 0; e < NE; ++e) acc[e] = 0.0f;
#pragma unroll
  for (int c = 0; c < 4; ++c) {
    const int k = (c * 64 + lane) * 4;
    f32x4 xv = *(const f32x4*)(xr + k);
#pragma unroll
    for (int e = 0; e < NE; ++e) {
      f32x4 gv = *(const f32x4*)(gw + e * HD + k);
      acc[e] += xv[0] * gv[0] + xv[1] * gv[1] + xv[2] * gv[2] + xv[3] * gv[3];
    }
  }
#pragma unroll
  for (int off = 32; off > 0; off >>= 1) {
#pragma unroll
    for (int e = 0; e < NE; ++e) acc[e] += __shfl_xor(acc[e], off, 64);
  }
  if (lane == 0) {
    int best = 0; float bv = acc[0];
#pragma unroll
    for (int e = 1; e < NE; ++e) if (acc[e] > bv) { bv = acc[e]; best = e; }
    top1[t] = best;
#pragma unroll
    for (int e = 0; e < NE; ++e) logits[(size_t)t * NE + e] = acc[e];
  }
}

__global__ void hist_k(const int* __restrict__ top1, int* __restrict__ counts) {
  int t = blockIdx.x * 256 + threadIdx.x;
  atomicAdd(&counts[top1[t]], 1);
}

__global__ void offsets_k(const int* __restrict__ counts, int* __restrict__ offsets) {
  if (threadIdx.x == 0) {
    int s = 0;
    for (int e = 0; e < NE; ++e) { offsets[e] = s; s += counts[e]; }
  }
}

__global__ void scatter_k(const int* __restrict__ top1, const int* __restrict__ offsets,
                          int* __restrict__ counts2, int* __restrict__ perm) {
  int t = blockIdx.x * 256 + threadIdx.x;
  int e = top1[t];
  int slot = atomicAdd(&counts2[e], 1);
  perm[offsets[e] + slot] = t;
}

// BM=128 tokens x BN=256 (128 gate-cols || 128 up-cols), BK=64, dbuf LDS, dist-2 prefetch.
// 8 waves 2Mx4N, wave tile 64x64. Gate/up fused via LDS epilogue exchange.
__global__ __launch_bounds__(512, 2) void gemm1_k(
    const float* __restrict__ x, const float* __restrict__ wg, const float* __restrict__ wu,
    const int* __restrict__ perm, const int* __restrict__ counts,
    const int* __restrict__ offsets, unsigned short* __restrict__ hidden) {
  const int e = blockIdx.z, mt = blockIdx.y, nt = blockIdx.x;
  const int ne = counts[e];
  if (mt * 128 >= ne) return;
  const int off = offsets[e];

  __shared__ __align__(16) char lds_c[98304];  // A dbuf 2x16KB @0, B dbuf 2x32KB @32768
#define BUFA1(p) (lds_c + (p) * 16384)
#define BUFB1(p) (lds_c + 32768 + (p) * 32768)

  const int tid = threadIdx.x;
  const int lane = tid & 63;
  const int wid = tid >> 6;
  const int wm = wid >> 2;            // 0..1
  const int wn = wid & 3;             // 0..3 (0,1=gate cols; 2,3=up cols)
  const int wrow = wm * 64;
  const int frow = lane & 15, khalf = lane >> 4;

  // staging: A row = tid>>2 (4 thr/row, 16 elems each); B row = tid>>1 (2 thr/row, 32 elems each)
  const int ar = tid >> 2, acE = (tid & 3) * 16;
  const int br = tid >> 1, bcE = (tid & 1) * 32;

  int lrA = mt * 128 + ar;
  const float* asrc = x + (size_t)((lrA < ne) ? perm[off + lrA] : perm[off]) * HD + acE;
  const float* bsrc = (br < 128)
      ? wg + ((size_t)e * ID + nt * 128 + br) * HD + bcE
      : wu + ((size_t)e * ID + nt * 128 + (br - 128)) * HD + bcE;

  f32x4 acc[4][4] = {};
  f32x4 ra[4], rb[8];

#define G1_LOAD(kt)                                                     \
  do {                                                                  \
    const float* a_ = asrc + (kt) * 64;                                 \
    const float* b_ = bsrc + (kt) * 64;                                 \
    _Pragma("unroll") for (int i = 0; i < 4; ++i) ra[i] = *(const f32x4*)(a_ + i * 4); \
    _Pragma("unroll") for (int i = 0; i < 8; ++i) rb[i] = *(const f32x4*)(b_ + i * 4); \
  } while (0)

#define G1_WRITE(p)                                                     \
  do {                                                                  \
    _Pragma("unroll") for (int i = 0; i < 2; ++i)                       \
      *(bf16x8*)(BUFA1(p) + SWZ(ar, acE * 2 + i * 16)) = pack8(ra[2 * i], ra[2 * i + 1]); \
    _Pragma("unroll") for (int i = 0; i < 4; ++i)                       \
      *(bf16x8*)(BUFB1(p) + SWZ(br, bcE * 2 + i * 16)) = pack8(rb[2 * i], rb[2 * i + 1]); \
  } while (0)

  const int NIT = HD / 64;
  G1_LOAD(0);
  G1_WRITE(0);
  bar_lgkm();
  G1_LOAD(1);

  for (int ks = 0; ks < NIT; ++ks) {
    const int cur = ks & 1;
    bf16x8 a0[4], b0[4];
#pragma unroll
    for (int mi = 0; mi < 4; ++mi)
      a0[mi] = *(const bf16x8*)(BUFA1(cur) + SWZ(wrow + mi * 16 + frow, khalf * 16));
#pragma unroll
    for (int ni = 0; ni < 4; ++ni)
      b0[ni] = *(const bf16x8*)(BUFB1(cur) + SWZ(wn * 64 + ni * 16 + frow, khalf * 16));
    if (ks + 1 < NIT) G1_WRITE(cur ^ 1);
    if (ks + 2 < NIT) G1_LOAD(ks + 2);
    __builtin_amdgcn_s_setprio(1);
#pragma unroll
    for (int mi = 0; mi < 4; ++mi)
#pragma unroll
      for (int ni = 0; ni < 4; ++ni)
        acc[mi][ni] = __builtin_amdgcn_mfma_f32_16x16x32_bf16(a0[mi], b0[ni], acc[mi][ni], 0, 0, 0);
    __builtin_amdgcn_s_setprio(0);
    bf16x8 a1[4], b1[4];
#pragma unroll
    for (int mi = 0; mi < 4; ++mi)
      a1[mi] = *(const bf16x8*)(BUFA1(cur) + SWZ(wrow + mi * 16 + frow, 64 + khalf * 16));
#pragma unroll
    for (int ni = 0; ni < 4; ++ni)
      b1[ni] = *(const bf16x8*)(BUFB1(cur) + SWZ(wn * 64 + ni * 16 + frow, 64 + khalf * 16));
    __builtin_amdgcn_s_setprio(1);
#pragma unroll
    for (int mi = 0; mi < 4; ++mi)
#pragma unroll
      for (int ni = 0; ni < 4; ++ni)
        acc[mi][ni] = __builtin_amdgcn_mfma_f32_16x16x32_bf16(a1[mi], b1[ni], acc[mi][ni], 0, 0, 0);
    __builtin_amdgcn_s_setprio(0);
    bar_lgkm();
  }
#undef G1_LOAD
#undef G1_WRITE

  // epilogue: gate waves dump to LDS exchange, up waves fuse gelu(g)*u -> hidden (bf16)
  float* exch = (float*)lds_c;  // [128][130] f32 = 66.6 KB
  if (wn < 2) {
#pragma unroll
    for (int mi = 0; mi < 4; ++mi)
#pragma unroll
      for (int ni = 0; ni < 4; ++ni)
#pragma unroll
        for (int j = 0; j < 4; ++j) {
          const int row = wrow + mi * 16 + khalf * 4 + j;
          const int col = wn * 64 + ni * 16 + frow;
          exch[row * 130 + col] = acc[mi][ni][j];
        }
  }
  bar_lgkm();
  if (wn >= 2) {
#pragma unroll
    for (int mi = 0; mi < 4; ++mi)
#pragma unroll
      for (int j = 0; j < 4; ++j) {
        const int row = wrow + mi * 16 + khalf * 4 + j;
        const int grow = mt * 128 + row;
        if (grow < ne) {
          unsigned short* hrow = hidden + (size_t)(off + grow) * ID + nt * 128;
#pragma unroll
          for (int ni = 0; ni < 4; ++ni) {
            const int col = (wn - 2) * 64 + ni * 16 + frow;
            float g = exch[row * 130 + col];
            __bf16 hb = (__bf16)(gelu_tanh(g) * acc[mi][ni][j]);
            hrow[col] = __builtin_bit_cast(unsigned short, hb);
          }
        }
      }
  }
}

// out[token,:] = hidden[p,:] @ wd[e]^T; BM=128, BN=128, BK=64, 256 thr / 4 waves (2x2),
// wave tile 64x64, dbuf LDS 64KB, dist-2 prefetch.
__global__ __launch_bounds__(256, 2) void gemm2_k(
    const unsigned short* __restrict__ hidden, const float* __restrict__ wd,
    const int* __restrict__ perm, const int* __restrict__ counts,
    const int* __restrict__ offsets, float* __restrict__ out) {
  const int e = blockIdx.z, mt = blockIdx.y, nt = blockIdx.x;
  const int ne = counts[e];
  if (mt * 128 >= ne) return;
  const int off = offsets[e];

  __shared__ __align__(16) char lds_c[65536];  // A dbuf 2x16KB @0, B dbuf 2x16KB @32768
#define BUFA2(p) (lds_c + (p) * 16384)
#define BUFB2(p) (lds_c + 32768 + (p) * 16384)

  const int tid = threadIdx.x;
  const int lane = tid & 63;
  const int wid = tid >> 6;
  const int wm = wid >> 1;            // 0..1
  const int wn = wid & 1;             // 0..1
  const int wrow = wm * 64, wcol = wn * 64;
  const int frow = lane & 15, khalf = lane >> 4;

  const int ar = tid >> 1, acE = (tid & 1) * 32;  // A: 2 thr/row, 32 bf16 elems each
  const int br = tid >> 1, bcE = (tid & 1) * 32;  // B: 2 thr/row, 32 fp32 elems each

  int lrA = mt * 128 + ar;
  const unsigned short* asrc =
      hidden + (size_t)(off + ((lrA < ne) ? lrA : (ne - 1))) * ID + acE;
  const float* bsrc = wd + ((size_t)e * HD + nt * 128 + br) * ID + bcE;

  f32x4 acc[4][4] = {};
  u16x8 rwa[4];
  f32x4 rb[8];

#define G2_LOAD(kt)                                                     \
  do {                                                                  \
    const unsigned short* a_ = asrc + (kt) * 64;                        \
    const float* b_ = bsrc + (kt) * 64;                                 \
    _Pragma("unroll") for (int i = 0; i < 4; ++i) rwa[i] = *(const u16x8*)(a_ + i * 8); \
    _Pragma("unroll") for (int i = 0; i < 8; ++i) rb[i] = *(const f32x4*)(b_ + i * 4); \
  } while (0)

#define G2_WRITE(p)                                                     \
  do {                                                                  \
    _Pragma("unroll") for (int i = 0; i < 4; ++i)                       \
      *(u16x8*)(BUFA2(p) + SWZ(ar, acE * 2 + i * 16)) = rwa[i];         \
    _Pragma("unroll") for (int i = 0; i < 4; ++i)                       \
      *(bf16x8*)(BUFB2(p) + SWZ(br, bcE * 2 + i * 16)) = pack8(rb[2 * i], rb[2 * i + 1]); \
  } while (0)

  const int NIT = ID / 64;
  G2_LOAD(0);
  G2_WRITE(0);
  bar_lgkm();
  G2_LOAD(1);

  for (int ks = 0; ks < NIT; ++ks) {
    const int cur = ks & 1;
    bf16x8 a0[4], b0[4];
#pragma unroll
    for (int mi = 0; mi < 4; ++mi)
      a0[mi] = *(const bf16x8*)(BUFA2(cur) + SWZ(wrow + mi * 16 + frow, khalf * 16));
#pragma unroll
    for (int ni = 0; ni < 4; ++ni)
      b0[ni] = *(const bf16x8*)(BUFB2(cur) + SWZ(wcol + ni * 16 + frow, khalf * 16));
    if (ks + 1 < NIT) G2_WRITE(cur ^ 1);
    if (ks + 2 < NIT) G2_LOAD(ks + 2);
    __builtin_amdgcn_s_setprio(1);
#pragma unroll
    for (int mi = 0; mi < 4; ++mi)
#pragma unroll
      for (int ni = 0; ni < 4; ++ni)
        acc[mi][ni] = __builtin_amdgcn_mfma_f32_16x16x32_bf16(a0[mi], b0[ni], acc[mi][ni], 0, 0, 0);
    __builtin_amdgcn_s_setprio(0);
    bf16x8 a1[4], b1[4];
#pragma unroll
    for (int mi = 0; mi < 4; ++mi)
      a1[mi] = *(const bf16x8*)(BUFA2(cur) + SWZ(wrow + mi * 16 + frow, 64 + khalf * 16));
#pragma unroll
    for (int ni = 0; ni < 4; ++ni)
      b1[ni] = *(const bf16x8*)(BUFB2(cur) + SWZ(wcol + ni * 16 + frow, 64 + khalf * 16));
    __builtin_amdgcn_s_setprio(1);
#pragma unroll
    for (int mi = 0; mi < 4; ++mi)
#pragma unroll
      for (int ni = 0; ni < 4; ++ni)
        acc[mi][ni] = __builtin_amdgcn_mfma_f32_16x16x32_bf16(a1[mi], b1[ni], acc[mi][ni], 0, 0, 0);
    __builtin_amdgcn_s_setprio(0);
    bar_lgkm();
  }
#undef G2_LOAD
#undef G2_WRITE

#pragma unroll
  for (int mi = 0; mi < 4; ++mi)
#pragma unroll
    for (int j = 0; j < 4; ++j) {
      const int row = wrow + mi * 16 + khalf * 4 + j;
      const int grow = mt * 128 + row;
      if (grow < ne) {
        const int t = perm[off + grow];
        float* orow = out + (size_t)t * HD + nt * 128 + wcol;
#pragma unroll
        for (int ni = 0; ni < 4; ++ni) orow[ni * 16 + frow] = acc[mi][ni][j];
      }
    }
}

extern "C" void kernel_launch(void* const* d_in, const int* in_sizes, int n_in,
                              void* d_out, int out_size, void* d_ws, size_t ws_size,
                              hipStream_t stream) {
  const float* x  = (const float*)d_in[0];
  const float* gw = (const float*)d_in[1];
  const float* wg = (const float*)d_in[2];
  const float* wu = (const float*)d_in[3];
  const float* wd = (const float*)d_in[4];
  float* out = (float*)d_out;
  float* logits = out + (size_t)TOK * HD;

  unsigned short* hidden = (unsigned short*)d_ws;
  int* meta = (int*)((char*)d_ws + (size_t)TOK * ID * sizeof(unsigned short));
  int* counts  = meta;        // [8]
  int* counts2 = meta + 8;    // [8]
  int* offsets = meta + 16;   // [8]
  int* top1    = meta + 24;   // [TOK]
  int* perm    = meta + 24 + TOK;  // [TOK]

  init_k<<<1, 64, 0, stream>>>(meta);
  router_k<<<TOK / 4, 256, 0, stream>>>(x, gw, logits, top1);
  hist_k<<<TOK / 256, 256, 0, stream>>>(top1, counts);
  offsets_k<<<1, 64, 0, stream>>>(counts, offsets);
  scatter_k<<<TOK / 256, 256, 0, stream>>>(top1, offsets, counts2, perm);
  gemm1_k<<<dim3(ID / 128, TOK / 128, NE), 512, 0, stream>>>(x, wg, wu, perm, counts, offsets, hidden);
  gemm2_k<<<dim3(HD / 128, TOK / 128, NE), 256, 0, stream>>>(hidden, wd, perm, counts, offsets, out);
}